// Round 16
// baseline (94.600 us; speedup 1.0000x reference)
//
#include <hip/hip_runtime.h>
#include <cstddef>

namespace {
constexpr int BATCH = 8;
constexpr int HDIM  = 80;
constexpr int WDIM  = 80;
constexpr int CDIM  = 128;
constexpr int NH    = 8;
constexpr int KD    = 16;
constexpr int BLK   = 8;
constexpr int HALO  = 3;
constexpr int KVK   = 14;              // BLOCK + 2*HALO
constexpr int EMB   = 128;
constexpr int HQ    = 10;
constexpr int WQ    = 10;
constexpr int MROWS = BATCH * HDIM * WDIM;  // 51200
constexpr int QKV_N = 384;

constexpr int KPAD  = 20;   // f16 stride K rows: 40B, qi*10dw mod 32 all distinct
constexpr int M2PAD = 32;   // f16 stride pre-shifted logit rows (packed, 64B)
constexpr int PEPAD = 20;   // f16 stride for peT rows
constexpr int APAD  = 136;  // f16 stride for GEMM LDS tiles
}

typedef _Float16 f16;
typedef f16   f16x2 __attribute__((ext_vector_type(2)));
typedef f16   f16x4 __attribute__((ext_vector_type(4)));
typedef f16   f16x8 __attribute__((ext_vector_type(8)));
typedef float f32x4 __attribute__((ext_vector_type(4)));

// ---------------- weight convert: f32 -> f16, transposed -------------------
__global__ __launch_bounds__(256) void convert_weights(
    const float* __restrict__ qd, const float* __restrict__ kvd,
    const float* __restrict__ od, const float* __restrict__ pew,
    const float* __restrict__ peh,
    f16* __restrict__ BTqkv, f16* __restrict__ BTo, f16* __restrict__ peT)
{
  const float QSC = 0.25f * 1.4426950408889634f;
  int tid = blockIdx.x * 256 + threadIdx.x;
  if (tid < 384 * 128) {
    int n = tid >> 7, c = tid & 127;
    float v = (n < 128) ? qd[c * 128 + n] * QSC : kvd[c * 256 + (n - 128)];
    BTqkv[tid] = (f16)v;
  } else if (tid < 384 * 128 + 128 * 128) {
    int j = tid - 384 * 128;
    int o = j >> 7, e = j & 127;
    BTo[j] = (f16)od[e * 128 + o];
  } else {
    int j = tid - (384 * 128 + 128 * 128);   // 0..1279
    int which = j / 640;
    int rem   = j - which * 640;
    int col   = rem / PEPAD;
    int d     = rem - col * PEPAD;
    float v = 0.f;
    if (col < 27 && d < 16) v = (which ? peh : pew)[d * 27 + col];
    peT[j] = (f16)v;
  }
}

// ---------------- GEMM 1 (MFMA): qkv_f16 = inputs @ W, K=128 single shot ---
__global__ __launch_bounds__(256, 4) void gemm_qkv_mfma(
    const float* __restrict__ A, const f16* __restrict__ BT,
    f16* __restrict__ C)
{
  __shared__ __align__(16) f16 b_lds[128 * APAD];

  const int bid = blockIdx.x;
  const int xcd = bid & 7;
  const int idx = bid >> 3;
  const int m0 = (xcd * 50 + idx / 3) * 128;
  const int n0 = (idx % 3) * 128;
  const int t  = threadIdx.x;

  #pragma unroll
  for (int it = 0; it < 8; ++it) {
    int item = t + it * 256;
    int row = item >> 4, c8 = item & 15;
    *reinterpret_cast<f16x8*>(&b_lds[row * APAD + c8 * 8]) =
        *reinterpret_cast<const f16x8*>(BT + (size_t)(n0 + row) * CDIM + c8 * 8);
  }
  __syncthreads();

  const int lane = t & 63, wv = t >> 6;
  const int g = lane >> 4, qi = lane & 15;

  const float* ap0 = A + (size_t)(m0 + wv * 32 + qi) * CDIM + g * 4;
  const float* ap1 = ap0 + 16 * CDIM;

  f32x4 acc[2][8];
  #pragma unroll
  for (int mt = 0; mt < 2; ++mt)
    #pragma unroll
    for (int nt = 0; nt < 8; ++nt) acc[mt][nt] = {0.f, 0.f, 0.f, 0.f};

  #pragma unroll
  for (int ks = 0; ks < 8; ++ks) {
    float4 fa0 = *reinterpret_cast<const float4*>(ap0 + ks * 16);
    float4 fa1 = *reinterpret_cast<const float4*>(ap1 + ks * 16);
    f16x4 a0 = {(f16)fa0.x, (f16)fa0.y, (f16)fa0.z, (f16)fa0.w};
    f16x4 a1 = {(f16)fa1.x, (f16)fa1.y, (f16)fa1.z, (f16)fa1.w};
    #pragma unroll
    for (int nt = 0; nt < 8; ++nt) {
      f16x4 bf = *reinterpret_cast<const f16x4*>(
          &b_lds[(nt * 16 + qi) * APAD + ks * 16 + g * 4]);
      acc[0][nt] = __builtin_amdgcn_mfma_f32_16x16x16f16(bf, a0, acc[0][nt], 0, 0, 0);
      acc[1][nt] = __builtin_amdgcn_mfma_f32_16x16x16f16(bf, a1, acc[1][nt], 0, 0, 0);
    }
  }

  #pragma unroll
  for (int mt = 0; mt < 2; ++mt) {
    int m = m0 + wv * 32 + mt * 16 + qi;
    #pragma unroll
    for (int nt = 0; nt < 8; ++nt) {
      f16x4 h = {(f16)acc[mt][nt][0], (f16)acc[mt][nt][1],
                 (f16)acc[mt][nt][2], (f16)acc[mt][nt][3]};
      *reinterpret_cast<f16x4*>(&C[(size_t)m * QKV_N + n0 + nt * 16 + g * 4]) = h;
    }
  }
}

// ---------------- Halo attention (r11 structure, LDS=20224B -> 8 blk/CU) ---
__global__ __launch_bounds__(256, 8) void halo_attn_mfma(
    const f16* __restrict__ qkv, const f16* __restrict__ peT,
    f16* __restrict__ O)
{
  __shared__ __align__(16) f16 k_lds[224 * KPAD];   // [slot][kd], 40B rows
  __shared__ __align__(16) f16 v_lds[224 * 16];     // [slot][kd] row-major
  __shared__ __align__(16) f16 m2_lds[64 * M2PAD];  // [q][kw 0..15 | 16+tt]

  // XCD-chunked swizzle: each XCD gets 800 contiguous logical blocks.
  const int d0w  = blockIdx.x;
  const int bid  = (d0w & 7) * 800 + (d0w >> 3);
  const int n    = bid & 7;
  const int tile = bid >> 3;
  const int tw   = tile % WQ;
  const int th   = (tile / WQ) % HQ;
  const int b    = tile / (WQ * HQ);
  const int t    = threadIdx.x;

  const int lane = t & 63;
  const int wv   = t >> 6;
  const int g    = lane >> 4;
  const int qi   = lane & 15;
  const int q0   = wv * 16;
  const int q    = q0 + qi;
  const int x    = q >> 3, y = q & 7;

  // ---- Q fragment straight from global ----
  const size_t qrow = ((size_t)(b * HDIM + th * BLK + x)) * WDIM + tw * BLK + y;
  f16x4 qf = *reinterpret_cast<const f16x4*>(&qkv[qrow * QKV_N + n * KD + g * 4]);

  // ---- stage K/V: 224 slots x 4 parts ----
  #pragma unroll
  for (int it = 0; it < 4; ++it) {
    int item = t + it * 256;
    if (item < 896) {
      int slot = item >> 2, part = item & 3;
      int kh = slot >> 4, kw = slot & 15;
      int hh = th * BLK - HALO + kh;
      int ww = tw * BLK - HALO + kw;
      f16x8 v = {};
      if ((unsigned)hh < (unsigned)HDIM && (unsigned)ww < (unsigned)WDIM) {
        size_t row = ((size_t)(b * HDIM + hh)) * WDIM + ww;
        v = *reinterpret_cast<const f16x8*>(
            &qkv[row * QKV_N + 128 + n * 32 + part * 8]);
      }
      if (part < 2) {
        // 40B rows: b128 would misalign on odd slots -> two b64 writes
        f16x4 vlo = {v[0], v[1], v[2], v[3]};
        f16x4 vhi = {v[4], v[5], v[6], v[7]};
        *reinterpret_cast<f16x4*>(&k_lds[slot * KPAD + part * 8]) = vlo;
        *reinterpret_cast<f16x4*>(&k_lds[slot * KPAD + part * 8 + 4]) = vhi;
      } else {
        *reinterpret_cast<f16x8*>(&v_lds[slot * 16 + (part - 2) * 8]) = v;
      }
    }
  }

  const f32x4 z4 = {0.f, 0.f, 0.f, 0.f};

  // ---- rel-logit tables M = Q @ pe, written PRE-SHIFTED per q ----
  #pragma unroll
  for (int which = 0; which < 2; ++which) {
    #pragma unroll
    for (int ct = 0; ct < 2; ++ct) {
      f16x4 pf = *reinterpret_cast<const f16x4*>(
          &peT[(which * 32 + ct * 16 + qi) * PEPAD + g * 4]);
      f32x4 mc = __builtin_amdgcn_mfma_f32_16x16x16f16(qf, pf, z4, 0, 0, 0);
      int colb = ct * 16 + qi;
      #pragma unroll
      for (int r = 0; r < 4; ++r) {
        int qr = q0 + g * 4 + r;
        if (which == 0) {
          int kw = colb - 13 + (qr & 7);
          if ((unsigned)kw < 16u) m2_lds[qr * M2PAD + kw] = (f16)mc[r];
        } else {
          int tt = colb - 13 + (qr >> 3);
          if ((unsigned)tt < 14u) m2_lds[qr * M2PAD + 16 + tt] = (f16)mc[r];
        }
      }
    }
  }

  // ---- vector reads of the pre-shifted table (intra-wave write->read) ----
  f16x4 rlwv = *reinterpret_cast<const f16x4*>(&m2_lds[q * M2PAD + g * 4]);
  f16x4 rh4[4];
  #pragma unroll
  for (int k = 0; k < 4; ++k)
    rh4[k] = *reinterpret_cast<const f16x4*>(&m2_lds[q * M2PAD + 16 + k * 4]);

  float rlw[4];
  #pragma unroll
  for (int r = 0; r < 4; ++r) rlw[r] = (float)rlwv[r];
  if (g == 3) { rlw[2] = -1e30f; rlw[3] = -1e30f; }   // kw=14,15 masked

  __syncthreads();

  // ---- S^T = K @ Q^T with positional logits as the accumulator init ----
  f32x4 s[14];
  #pragma unroll
  for (int tt = 0; tt < 14; ++tt) {
    float rh = (float)rh4[tt >> 2][tt & 3];
    f32x4 c;
    c[0] = rlw[0] + rh; c[1] = rlw[1] + rh;
    c[2] = rlw[2] + rh; c[3] = rlw[3] + rh;
    f16x4 kf = *reinterpret_cast<const f16x4*>(&k_lds[(tt * 16 + qi) * KPAD + g * 4]);
    s[tt] = __builtin_amdgcn_mfma_f32_16x16x16f16(kf, qf, c, 0, 0, 0);
  }

  // ---- softmax, no max pass: exp2(s)/sum ----
  float ls = 0.f;
  f16x4 pf[14];
  #pragma unroll
  for (int tt = 0; tt < 14; ++tt) {
    float p0 = __builtin_amdgcn_exp2f(s[tt][0]);
    float p1 = __builtin_amdgcn_exp2f(s[tt][1]);
    float p2 = __builtin_amdgcn_exp2f(s[tt][2]);
    float p3 = __builtin_amdgcn_exp2f(s[tt][3]);
    ls += (p0 + p1) + (p2 + p3);
    f16x2 lo = __builtin_bit_cast(f16x2, __builtin_amdgcn_cvt_pkrtz(p0, p1));
    f16x2 hi = __builtin_bit_cast(f16x2, __builtin_amdgcn_cvt_pkrtz(p2, p3));
    pf[tt][0] = lo[0]; pf[tt][1] = lo[1];
    pf[tt][2] = hi[0]; pf[tt][3] = hi[1];
  }
  ls += __shfl_xor(ls, 16);
  ls += __shfl_xor(ls, 32);

  // ---- PV: identity-MFMA V transpose ----
  f16x4 iv;
  #pragma unroll
  for (int r = 0; r < 4; ++r)
    iv[r] = (qi == g * 4 + r) ? (f16)1.f : (f16)0.f;

  f32x4 acc = z4;
  #pragma unroll
  for (int tt = 0; tt < 14; ++tt) {
    f16x4 xv = *reinterpret_cast<const f16x4*>(&v_lds[(tt * 16 + qi) * 16 + g * 4]);
    f32x4 tD = __builtin_amdgcn_mfma_f32_16x16x16f16(xv, iv, z4, 0, 0, 0);
    f16x2 lo = __builtin_bit_cast(f16x2, __builtin_amdgcn_cvt_pkrtz(tD[0], tD[1]));
    f16x2 hi = __builtin_bit_cast(f16x2, __builtin_amdgcn_cvt_pkrtz(tD[2], tD[3]));
    f16x4 vf;
    vf[0] = lo[0]; vf[1] = lo[1]; vf[2] = hi[0]; vf[3] = hi[1];
    acc = __builtin_amdgcn_mfma_f32_16x16x16f16(vf, pf[tt], acc, 0, 0, 0);
  }

  const float inv = __builtin_amdgcn_rcpf(ls);
  f16x4 o = {(f16)(acc[0] * inv), (f16)(acc[1] * inv),
             (f16)(acc[2] * inv), (f16)(acc[3] * inv)};
  *reinterpret_cast<f16x4*>(&O[qrow * EMB + n * KD + g * 4]) = o;
}

// ---------------- GEMM 2 (MFMA): out_f32 = O_f16 @ od, BM=64 ---------------
__global__ __launch_bounds__(256, 4) void gemm_out_mfma(
    const f16* __restrict__ A, const f16* __restrict__ BT,
    float* __restrict__ C)
{
  __shared__ __align__(16) f16 b_lds[128 * APAD];

  const int m0 = blockIdx.x * 64;
  const int t  = threadIdx.x;

  #pragma unroll
  for (int it = 0; it < 8; ++it) {
    int item = t + it * 256;
    int row = item >> 4, c8 = item & 15;
    *reinterpret_cast<f16x8*>(&b_lds[row * APAD + c8 * 8]) =
        *reinterpret_cast<const f16x8*>(BT + (size_t)row * EMB + c8 * 8);
  }
  __syncthreads();

  const int lane = t & 63, wv = t >> 6;
  const int g = lane >> 4, qi = lane & 15;

  const f16* ap = A + (size_t)(m0 + wv * 16 + qi) * EMB + g * 4;

  f32x4 acc[8];
  #pragma unroll
  for (int nt = 0; nt < 8; ++nt) acc[nt] = {0.f, 0.f, 0.f, 0.f};

  #pragma unroll
  for (int ks = 0; ks < 8; ++ks) {
    f16x4 a = *reinterpret_cast<const f16x4*>(ap + ks * 16);
    #pragma unroll
    for (int nt = 0; nt < 8; ++nt) {
      f16x4 bf = *reinterpret_cast<const f16x4*>(
          &b_lds[(nt * 16 + qi) * APAD + ks * 16 + g * 4]);
      acc[nt] = __builtin_amdgcn_mfma_f32_16x16x16f16(bf, a, acc[nt], 0, 0, 0);
    }
  }

  const int m = m0 + wv * 16 + qi;
  #pragma unroll
  for (int nt = 0; nt < 8; ++nt) {
    f32x4 v = acc[nt];
    *reinterpret_cast<float4*>(&C[(size_t)m * CDIM + nt * 16 + g * 4]) =
        *reinterpret_cast<float4*>(&v);
  }
}

extern "C" void kernel_launch(void* const* d_in, const int* in_sizes, int n_in,
                              void* d_out, int out_size, void* d_ws, size_t ws_size,
                              hipStream_t stream)
{
  const float* inputs = (const float*)d_in[0];
  const float* qd     = (const float*)d_in[1];
  const float* kvd    = (const float*)d_in[2];
  const float* od     = (const float*)d_in[3];
  const float* pew    = (const float*)d_in[4];
  const float* peh    = (const float*)d_in[5];

  char* ws = (char*)d_ws;
  f16* qkv   = (f16*)ws;                                   // 51200x384 f16
  f16* O     = (f16*)(ws + (size_t)MROWS * QKV_N * 2);     // 51200x128 f16
  f16* BTqkv = (f16*)(ws + (size_t)MROWS * QKV_N * 2 + (size_t)MROWS * EMB * 2);
  f16* BTo   = BTqkv + 384 * 128;
  f16* peT   = BTo + 128 * 128;                            // 2*32*20 f16
  float* out = (float*)d_out;

  convert_weights<<<dim3(261), 256, 0, stream>>>(qd, kvd, od, pew, peh,
                                                 BTqkv, BTo, peT);
  gemm_qkv_mfma<<<dim3(1200), 256, 0, stream>>>(inputs, BTqkv, qkv);
  halo_attn_mfma<<<dim3(BATCH * HQ * WQ * NH), 256, 0, stream>>>(qkv, peT, O);
  gemm_out_mfma<<<dim3(MROWS / 64), 256, 0, stream>>>(O, BTo, out);
}

// Round 17
// 73.095 us; speedup vs baseline: 1.2942x; 1.2942x over previous
//
#include <hip/hip_runtime.h>
#include <cstddef>

namespace {
constexpr int BATCH = 8;
constexpr int HDIM  = 80;
constexpr int WDIM  = 80;
constexpr int CDIM  = 128;
constexpr int NH    = 8;
constexpr int KD    = 16;
constexpr int BLK   = 8;
constexpr int HALO  = 3;
constexpr int KVK   = 14;              // BLOCK + 2*HALO
constexpr int EMB   = 128;
constexpr int HQ    = 10;
constexpr int WQ    = 10;
constexpr int MROWS = BATCH * HDIM * WDIM;  // 51200
constexpr int QKV_N = 384;

constexpr int KPAD  = 24;   // f16 stride for K rows (16B-aligned for b128 writes)
constexpr int M2PAD = 36;   // f16 stride pre-shifted logit rows
constexpr int PEPAD = 20;   // f16 stride for peT rows
constexpr int APAD  = 136;  // f16 stride for GEMM LDS tiles
}

typedef _Float16 f16;
typedef f16   f16x2 __attribute__((ext_vector_type(2)));
typedef f16   f16x4 __attribute__((ext_vector_type(4)));
typedef f16   f16x8 __attribute__((ext_vector_type(8)));
typedef float f32x4 __attribute__((ext_vector_type(4)));

// ---------------- weight convert: f32 -> f16, transposed -------------------
__global__ __launch_bounds__(256) void convert_weights(
    const float* __restrict__ qd, const float* __restrict__ kvd,
    const float* __restrict__ od, const float* __restrict__ pew,
    const float* __restrict__ peh,
    f16* __restrict__ BTqkv, f16* __restrict__ BTo, f16* __restrict__ peT)
{
  const float QSC = 0.25f * 1.4426950408889634f;
  int tid = blockIdx.x * 256 + threadIdx.x;
  if (tid < 384 * 128) {
    int n = tid >> 7, c = tid & 127;
    float v = (n < 128) ? qd[c * 128 + n] * QSC : kvd[c * 256 + (n - 128)];
    BTqkv[tid] = (f16)v;
  } else if (tid < 384 * 128 + 128 * 128) {
    int j = tid - 384 * 128;
    int o = j >> 7, e = j & 127;
    BTo[j] = (f16)od[e * 128 + o];
  } else {
    int j = tid - (384 * 128 + 128 * 128);   // 0..1279
    int which = j / 640;
    int rem   = j - which * 640;
    int col   = rem / PEPAD;
    int d     = rem - col * PEPAD;
    float v = 0.f;
    if (col < 27 && d < 16) v = (which ? peh : pew)[d * 27 + col];
    peT[j] = (f16)v;
  }
}

// ---------------- GEMM 1 (MFMA): qkv_f16 = inputs @ W, K=128 single shot ---
__global__ __launch_bounds__(256, 4) void gemm_qkv_mfma(
    const float* __restrict__ A, const f16* __restrict__ BT,
    f16* __restrict__ C)
{
  __shared__ __align__(16) f16 b_lds[128 * APAD];

  const int bid = blockIdx.x;
  const int xcd = bid & 7;
  const int idx = bid >> 3;
  const int m0 = (xcd * 50 + idx / 3) * 128;
  const int n0 = (idx % 3) * 128;
  const int t  = threadIdx.x;

  #pragma unroll
  for (int it = 0; it < 8; ++it) {
    int item = t + it * 256;
    int row = item >> 4, c8 = item & 15;
    *reinterpret_cast<f16x8*>(&b_lds[row * APAD + c8 * 8]) =
        *reinterpret_cast<const f16x8*>(BT + (size_t)(n0 + row) * CDIM + c8 * 8);
  }
  __syncthreads();

  const int lane = t & 63, wv = t >> 6;
  const int g = lane >> 4, qi = lane & 15;

  const float* ap0 = A + (size_t)(m0 + wv * 32 + qi) * CDIM + g * 4;
  const float* ap1 = ap0 + 16 * CDIM;

  f32x4 acc[2][8];
  #pragma unroll
  for (int mt = 0; mt < 2; ++mt)
    #pragma unroll
    for (int nt = 0; nt < 8; ++nt) acc[mt][nt] = {0.f, 0.f, 0.f, 0.f};

  #pragma unroll
  for (int ks = 0; ks < 8; ++ks) {
    float4 fa0 = *reinterpret_cast<const float4*>(ap0 + ks * 16);
    float4 fa1 = *reinterpret_cast<const float4*>(ap1 + ks * 16);
    f16x4 a0 = {(f16)fa0.x, (f16)fa0.y, (f16)fa0.z, (f16)fa0.w};
    f16x4 a1 = {(f16)fa1.x, (f16)fa1.y, (f16)fa1.z, (f16)fa1.w};
    #pragma unroll
    for (int nt = 0; nt < 8; ++nt) {
      f16x4 bf = *reinterpret_cast<const f16x4*>(
          &b_lds[(nt * 16 + qi) * APAD + ks * 16 + g * 4]);
      acc[0][nt] = __builtin_amdgcn_mfma_f32_16x16x16f16(bf, a0, acc[0][nt], 0, 0, 0);
      acc[1][nt] = __builtin_amdgcn_mfma_f32_16x16x16f16(bf, a1, acc[1][nt], 0, 0, 0);
    }
  }

  #pragma unroll
  for (int mt = 0; mt < 2; ++mt) {
    int m = m0 + wv * 32 + mt * 16 + qi;
    #pragma unroll
    for (int nt = 0; nt < 8; ++nt) {
      f16x4 h = {(f16)acc[mt][nt][0], (f16)acc[mt][nt][1],
                 (f16)acc[mt][nt][2], (f16)acc[mt][nt][3]};
      *reinterpret_cast<f16x4*>(&C[(size_t)m * QKV_N + n0 + nt * 16 + g * 4]) = h;
    }
  }
}

// ---------------- Halo attention (MFMA f16, identity-MFMA V transpose) -----
// LDS = 22528B -> 7 blocks/CU.
__global__ __launch_bounds__(256, 4) void halo_attn_mfma(
    const f16* __restrict__ qkv, const f16* __restrict__ peT,
    f16* __restrict__ O)
{
  __shared__ __align__(16) f16 k_lds[224 * KPAD];   // [slot][kd]
  __shared__ __align__(16) f16 v_lds[224 * 16];     // [slot][kd] row-major
  __shared__ __align__(16) f16 m2_lds[64 * M2PAD];  // [q][kw 0..15 | 16+tt]

  // XCD-chunked swizzle: each XCD gets 800 contiguous logical blocks.
  const int d0w  = blockIdx.x;
  const int bid  = (d0w & 7) * 800 + (d0w >> 3);
  const int n    = bid & 7;
  const int tile = bid >> 3;
  const int tw   = tile % WQ;
  const int th   = (tile / WQ) % HQ;
  const int b    = tile / (WQ * HQ);
  const int t    = threadIdx.x;

  const int lane = t & 63;
  const int wv   = t >> 6;
  const int g    = lane >> 4;
  const int qi   = lane & 15;
  const int q0   = wv * 16;
  const int q    = q0 + qi;
  const int x    = q >> 3, y = q & 7;

  // ---- Q fragment straight from global ----
  const size_t qrow = ((size_t)(b * HDIM + th * BLK + x)) * WDIM + tw * BLK + y;
  f16x4 qf = *reinterpret_cast<const f16x4*>(&qkv[qrow * QKV_N + n * KD + g * 4]);

  // ---- stage K/V: 224 slots x 4 parts, ALL vector b128 writes ----
  #pragma unroll
  for (int it = 0; it < 4; ++it) {
    int item = t + it * 256;
    if (item < 896) {
      int slot = item >> 2, part = item & 3;
      int kh = slot >> 4, kw = slot & 15;
      int hh = th * BLK - HALO + kh;
      int ww = tw * BLK - HALO + kw;
      f16x8 v = {};
      if ((unsigned)hh < (unsigned)HDIM && (unsigned)ww < (unsigned)WDIM) {
        size_t row = ((size_t)(b * HDIM + hh)) * WDIM + ww;
        v = *reinterpret_cast<const f16x8*>(
            &qkv[row * QKV_N + 128 + n * 32 + part * 8]);
      }
      if (part < 2)
        *reinterpret_cast<f16x8*>(&k_lds[slot * KPAD + part * 8]) = v;
      else
        *reinterpret_cast<f16x8*>(&v_lds[slot * 16 + (part - 2) * 8]) = v;
    }
  }

  const f32x4 z4 = {0.f, 0.f, 0.f, 0.f};

  // ---- rel-logit tables M = Q @ pe, written PRE-SHIFTED per q ----
  #pragma unroll
  for (int which = 0; which < 2; ++which) {
    #pragma unroll
    for (int ct = 0; ct < 2; ++ct) {
      f16x4 pf = *reinterpret_cast<const f16x4*>(
          &peT[(which * 32 + ct * 16 + qi) * PEPAD + g * 4]);
      f32x4 mc = __builtin_amdgcn_mfma_f32_16x16x16f16(qf, pf, z4, 0, 0, 0);
      int colb = ct * 16 + qi;
      #pragma unroll
      for (int r = 0; r < 4; ++r) {
        int qr = q0 + g * 4 + r;
        if (which == 0) {
          int kw = colb - 13 + (qr & 7);
          if ((unsigned)kw < 16u) m2_lds[qr * M2PAD + kw] = (f16)mc[r];
        } else {
          int tt = colb - 13 + (qr >> 3);
          if ((unsigned)tt < 14u) m2_lds[qr * M2PAD + 16 + tt] = (f16)mc[r];
        }
      }
    }
  }

  // ---- vector reads of the pre-shifted table (intra-wave write->read) ----
  f16x4 rlwv = *reinterpret_cast<const f16x4*>(&m2_lds[q * M2PAD + g * 4]);
  f16x4 rh4[4];
  #pragma unroll
  for (int k = 0; k < 4; ++k)
    rh4[k] = *reinterpret_cast<const f16x4*>(&m2_lds[q * M2PAD + 16 + k * 4]);

  float rlw[4];
  #pragma unroll
  for (int r = 0; r < 4; ++r) rlw[r] = (float)rlwv[r];
  if (g == 3) { rlw[2] = -1e30f; rlw[3] = -1e30f; }   // kw=14,15 masked

  __syncthreads();

  // ---- S^T = K @ Q^T with positional logits as the accumulator init ----
  f32x4 s[14];
  #pragma unroll
  for (int tt = 0; tt < 14; ++tt) {
    float rh = (float)rh4[tt >> 2][tt & 3];
    f32x4 c;
    c[0] = rlw[0] + rh; c[1] = rlw[1] + rh;
    c[2] = rlw[2] + rh; c[3] = rlw[3] + rh;
    f16x4 kf = *reinterpret_cast<const f16x4*>(&k_lds[(tt * 16 + qi) * KPAD + g * 4]);
    s[tt] = __builtin_amdgcn_mfma_f32_16x16x16f16(kf, qf, c, 0, 0, 0);
  }

  // ---- softmax, no max pass: exp2(s)/sum ----
  float ls = 0.f;
  f16x4 pf[14];
  #pragma unroll
  for (int tt = 0; tt < 14; ++tt) {
    float p0 = __builtin_amdgcn_exp2f(s[tt][0]);
    float p1 = __builtin_amdgcn_exp2f(s[tt][1]);
    float p2 = __builtin_amdgcn_exp2f(s[tt][2]);
    float p3 = __builtin_amdgcn_exp2f(s[tt][3]);
    ls += (p0 + p1) + (p2 + p3);
    f16x2 lo = __builtin_bit_cast(f16x2, __builtin_amdgcn_cvt_pkrtz(p0, p1));
    f16x2 hi = __builtin_bit_cast(f16x2, __builtin_amdgcn_cvt_pkrtz(p2, p3));
    pf[tt][0] = lo[0]; pf[tt][1] = lo[1];
    pf[tt][2] = hi[0]; pf[tt][3] = hi[1];
  }
  ls += __shfl_xor(ls, 16);
  ls += __shfl_xor(ls, 32);

  // ---- PV: identity-MFMA V transpose ----
  f16x4 iv;
  #pragma unroll
  for (int r = 0; r < 4; ++r)
    iv[r] = (qi == g * 4 + r) ? (f16)1.f : (f16)0.f;

  f32x4 acc = z4;
  #pragma unroll
  for (int tt = 0; tt < 14; ++tt) {
    f16x4 xv = *reinterpret_cast<const f16x4*>(&v_lds[(tt * 16 + qi) * 16 + g * 4]);
    f32x4 tD = __builtin_amdgcn_mfma_f32_16x16x16f16(xv, iv, z4, 0, 0, 0);
    f16x2 lo = __builtin_bit_cast(f16x2, __builtin_amdgcn_cvt_pkrtz(tD[0], tD[1]));
    f16x2 hi = __builtin_bit_cast(f16x2, __builtin_amdgcn_cvt_pkrtz(tD[2], tD[3]));
    f16x4 vf;
    vf[0] = lo[0]; vf[1] = lo[1]; vf[2] = hi[0]; vf[3] = hi[1];
    acc = __builtin_amdgcn_mfma_f32_16x16x16f16(vf, pf[tt], acc, 0, 0, 0);
  }

  const float inv = __builtin_amdgcn_rcpf(ls);
  f16x4 o = {(f16)(acc[0] * inv), (f16)(acc[1] * inv),
             (f16)(acc[2] * inv), (f16)(acc[3] * inv)};
  *reinterpret_cast<f16x4*>(&O[qrow * EMB + n * KD + g * 4]) = o;
}

// ---------------- GEMM 2 (MFMA): out_f32 = O_f16 @ od, BM=64 ---------------
__global__ __launch_bounds__(256, 4) void gemm_out_mfma(
    const f16* __restrict__ A, const f16* __restrict__ BT,
    float* __restrict__ C)
{
  __shared__ __align__(16) f16 b_lds[128 * APAD];

  const int m0 = blockIdx.x * 64;
  const int t  = threadIdx.x;

  #pragma unroll
  for (int it = 0; it < 8; ++it) {
    int item = t + it * 256;
    int row = item >> 4, c8 = item & 15;
    *reinterpret_cast<f16x8*>(&b_lds[row * APAD + c8 * 8]) =
        *reinterpret_cast<const f16x8*>(BT + (size_t)row * EMB + c8 * 8);
  }
  __syncthreads();

  const int lane = t & 63, wv = t >> 6;
  const int g = lane >> 4, qi = lane & 15;

  const f16* ap = A + (size_t)(m0 + wv * 16 + qi) * EMB + g * 4;

  f32x4 acc[8];
  #pragma unroll
  for (int nt = 0; nt < 8; ++nt) acc[nt] = {0.f, 0.f, 0.f, 0.f};

  #pragma unroll
  for (int ks = 0; ks < 8; ++ks) {
    f16x4 a = *reinterpret_cast<const f16x4*>(ap + ks * 16);
    #pragma unroll
    for (int nt = 0; nt < 8; ++nt) {
      f16x4 bf = *reinterpret_cast<const f16x4*>(
          &b_lds[(nt * 16 + qi) * APAD + ks * 16 + g * 4]);
      acc[nt] = __builtin_amdgcn_mfma_f32_16x16x16f16(bf, a, acc[nt], 0, 0, 0);
    }
  }

  const int m = m0 + wv * 16 + qi;
  #pragma unroll
  for (int nt = 0; nt < 8; ++nt) {
    f32x4 v = acc[nt];
    *reinterpret_cast<float4*>(&C[(size_t)m * CDIM + nt * 16 + g * 4]) =
        *reinterpret_cast<float4*>(&v);
  }
}

extern "C" void kernel_launch(void* const* d_in, const int* in_sizes, int n_in,
                              void* d_out, int out_size, void* d_ws, size_t ws_size,
                              hipStream_t stream)
{
  const float* inputs = (const float*)d_in[0];
  const float* qd     = (const float*)d_in[1];
  const float* kvd    = (const float*)d_in[2];
  const float* od     = (const float*)d_in[3];
  const float* pew    = (const float*)d_in[4];
  const float* peh    = (const float*)d_in[5];

  char* ws = (char*)d_ws;
  f16* qkv   = (f16*)ws;                                   // 51200x384 f16
  f16* O     = (f16*)(ws + (size_t)MROWS * QKV_N * 2);     // 51200x128 f16
  f16* BTqkv = (f16*)(ws + (size_t)MROWS * QKV_N * 2 + (size_t)MROWS * EMB * 2);
  f16* BTo   = BTqkv + 384 * 128;
  f16* peT   = BTo + 128 * 128;                            // 2*32*20 f16
  float* out = (float*)d_out;

  convert_weights<<<dim3(261), 256, 0, stream>>>(qd, kvd, od, pew, peh,
                                                 BTqkv, BTo, peT);
  gemm_qkv_mfma<<<dim3(1200), 256, 0, stream>>>(inputs, BTqkv, qkv);
  halo_attn_mfma<<<dim3(BATCH * HQ * WQ * NH), 256, 0, stream>>>(qkv, peT, O);
  gemm_out_mfma<<<dim3(MROWS / 64), 256, 0, stream>>>(O, BTo, out);
}